// Round 11
// baseline (284.441 us; speedup 1.0000x reference)
//
#include <hip/hip_runtime.h>

typedef __bf16 bf16;
typedef __bf16 bf16x4 __attribute__((ext_vector_type(4)));
typedef __bf16 bf16x8 __attribute__((ext_vector_type(8)));
typedef float f32x4 __attribute__((ext_vector_type(4)));

#define D_MODEL 1024
#define SEQ 2048
#define NB 2
#define LOG2E 1.4426950408889634f

// async global->LDS, 16B per lane; LDS dest = wave-uniform base + lane*16
__device__ __forceinline__ void glds16(const bf16* g, bf16* l) {
    __builtin_amdgcn_global_load_lds(
        (const __attribute__((address_space(1))) void*)g,
        (__attribute__((address_space(3))) void*)l, 16, 0, 0);
}

// ---------------- fused prep (weights W^T + bias concat) + norm1 ----------------
__device__ __forceinline__ void tile_tcvt(
    const float* __restrict__ src, int rows, int cols, bf16* __restrict__ dst,
    int bx, int by, bf16 (*t)[72])
{
    int tid = threadIdx.x;
    int k0 = by * 64, n0 = bx * 64;
    int r = tid >> 2, c = (tid & 3) * 16;
    const float4* s = (const float4*)(src + (size_t)(k0 + r) * cols + n0 + c);
#pragma unroll
    for (int q = 0; q < 4; ++q) {
        float4 v = s[q];
        t[c + q * 4 + 0][r] = (bf16)v.x;
        t[c + q * 4 + 1][r] = (bf16)v.y;
        t[c + q * 4 + 2][r] = (bf16)v.z;
        t[c + q * 4 + 3][r] = (bf16)v.w;
    }
    __syncthreads();
    bf16* d = dst + (size_t)(n0 + r) * rows + k0 + c;
    *(bf16x8*)(d)     = *(const bf16x8*)&t[r][c];
    *(bf16x8*)(d + 8) = *(const bf16x8*)&t[r][c + 8];
}

__device__ __forceinline__ void norm_row(
    const float* __restrict__ X, const float* __restrict__ alpha,
    const float* __restrict__ beta, bf16* __restrict__ Y, int row)
{
    int tid = threadIdx.x;
    float4 v = ((const float4*)(X + (size_t)row * D_MODEL))[tid];
    float s = v.x + v.y + v.z + v.w;
    float ss = v.x*v.x + v.y*v.y + v.z*v.z + v.w*v.w;
#pragma unroll
    for (int off = 1; off < 64; off <<= 1) {
        s  += __shfl_xor(s, off, 64);
        ss += __shfl_xor(ss, off, 64);
    }
    __shared__ float sd[8];
    int wave = tid >> 6, lane = tid & 63;
    if (lane == 0) { sd[wave] = s; sd[4 + wave] = ss; }
    __syncthreads();
    s  = sd[0] + sd[1] + sd[2] + sd[3];
    ss = sd[4] + sd[5] + sd[6] + sd[7];
    float mean = s * (1.0f / 1024.0f);
    float var  = (ss - s * mean) * (1.0f / 1023.0f);
    float rs = rsqrtf(var + 1e-6f);
    float4 a = ((const float4*)alpha)[tid];
    float4 bt = ((const float4*)beta)[tid];
    bf16x4 o;
    o[0] = (bf16)(a.x * (v.x - mean) * rs + bt.x);
    o[1] = (bf16)(a.y * (v.y - mean) * rs + bt.y);
    o[2] = (bf16)(a.z * (v.z - mean) * rs + bt.z);
    o[3] = (bf16)(a.w * (v.w - mean) * rs + bt.w);
    *(bf16x4*)(Y + (size_t)row * D_MODEL + tid * 4) = o;
}

__global__ __launch_bounds__(256) void prep_norm_kernel(
    const float* __restrict__ x, const float* __restrict__ alpha1,
    const float* __restrict__ beta1, bf16* __restrict__ xn,
    const float* __restrict__ Wq, const float* __restrict__ Wk,
    const float* __restrict__ Wv, const float* __restrict__ Wo,
    const float* __restrict__ W1, const float* __restrict__ W2,
    const float* __restrict__ bq, const float* __restrict__ bk,
    const float* __restrict__ bv,
    bf16* __restrict__ Wqkv_t, bf16* __restrict__ Wo_t,
    bf16* __restrict__ W1_t, bf16* __restrict__ W2_t,
    float* __restrict__ b_qkv)
{
    __shared__ bf16 t[64][72];
    int id = blockIdx.x;
    if (id < 4096) {
        norm_row(x, alpha1, beta1, xn, id);
        return;
    }
    id -= 4096;
    if (id < 1024) {
        int which = id >> 8, tile = id & 255;
        const float* src = which == 0 ? Wq : which == 1 ? Wk : which == 2 ? Wv : Wo;
        bf16* dst = which == 3 ? Wo_t : Wqkv_t + (size_t)which * 1024 * 1024;
        tile_tcvt(src, 1024, 1024, dst, tile & 15, tile >> 4, t);
    } else if (id < 1152) {
        int tile = id - 1024;
        tile_tcvt(W1, 1024, 512, W1_t, tile & 7, tile >> 3, t);
    } else if (id < 1280) {
        int tile = id - 1152;
        tile_tcvt(W2, 512, 1024, W2_t, tile & 15, tile >> 4, t);
    } else {
        int i = (id - 1280) * 256 + threadIdx.x;
        float v;
        if (i < 1024) v = bq[i];
        else if (i < 2048) v = bk[i - 1024];
        else v = bv[i - 2048];
        b_qkv[i] = v;
    }
}

// ---------------- LayerNorm standalone (norm2) ----------------
__global__ __launch_bounds__(256) void norm_kernel(
    const float* __restrict__ X, const float* __restrict__ alpha,
    const float* __restrict__ beta, bf16* __restrict__ Y)
{
    norm_row(X, alpha, beta, Y, blockIdx.x);
}

// ---------------- GEMM: C = A(MxK,lda)@Bt^T + bias [+Rb/+Rf] [ReLU] ----------------
// Tile BM x BN, K-step 32*KU, 4 waves (2x2), mfma 16x16x32.
// BM=64: halves per-block work -> doubles grid (tail/TLP fix for short-K GEMMs).
// BN=32: B-tile staged by first 128 threads only (wave-uniform guard).
// VFUSE: n>=2048 columns (V proj) written transposed into vT[bh][d][s].
template <typename OutT, int BM, int BN, int KU, bool VFUSE>
__global__ __launch_bounds__(256) void gemm128(
    const bf16* __restrict__ A, const bf16* __restrict__ Bt,
    const float* __restrict__ bias, const bf16* __restrict__ Rb,
    const float* __restrict__ Rf, OutT* __restrict__ C, bf16* __restrict__ vT,
    int M, int N, int K, int lda, int relu)
{
    constexpr int MT = BM / 32;
    constexpr int NT = BN / 32;
    constexpr int ASTR = BM * 32;
    constexpr int BSTR = BN * 32;
    __shared__ bf16 As[ASTR * KU];
    __shared__ bf16 Bs[BSTR * KU];

    int tid = threadIdx.x;
    int wave = tid >> 6, lane = tid & 63;
    int quad = lane >> 4, l16 = lane & 15;
    int m0 = blockIdx.y * BM, n0 = blockIdx.x * BN;
    int wm = (wave >> 1) * (BM / 2), wn = (wave & 1) * (BN / 2);

    f32x4 acc[MT][NT] = {};

    const bf16* ga = A  + (size_t)(m0 + (tid >> 2)) * lda + (tid & 3) * 8;
    const bf16* gb = Bt + (size_t)(n0 + (tid >> 2)) * K   + (tid & 3) * 8;
    bf16* lAs = As + wave * 512;
    bf16* lBs = Bs + wave * 512;

    for (int k0 = 0; k0 < K; k0 += 32 * KU) {
        __syncthreads();
#pragma unroll
        for (int u = 0; u < KU; ++u) {
            glds16(ga + k0 + u * 32, lAs + u * ASTR);
            if (BM == 128)
                glds16(ga + (size_t)64 * lda + k0 + u * 32, lAs + u * ASTR + 2048);
            if (BN >= 64 || tid < 128)
                glds16(gb + k0 + u * 32, lBs + u * BSTR);
            if (BN == 128) glds16(gb + (size_t)64 * K + k0 + u * 32, lBs + u * BSTR + 2048);
        }
        __syncthreads();
#pragma unroll
        for (int u = 0; u < KU; ++u) {
            bf16x8 af[MT], bfr[NT];
#pragma unroll
            for (int mt = 0; mt < MT; ++mt)
                af[mt] = *(const bf16x8*)(As + u * ASTR + (wm + mt * 16 + l16) * 32 + quad * 8);
#pragma unroll
            for (int nt = 0; nt < NT; ++nt)
                bfr[nt] = *(const bf16x8*)(Bs + u * BSTR + (wn + nt * 16 + l16) * 32 + quad * 8);
#pragma unroll
            for (int mt = 0; mt < MT; ++mt)
#pragma unroll
                for (int nt = 0; nt < NT; ++nt)
                    acc[mt][nt] = __builtin_amdgcn_mfma_f32_16x16x32_bf16(af[mt], bfr[nt], acc[mt][nt], 0, 0, 0);
        }
    }

#pragma unroll
    for (int nt = 0; nt < NT; ++nt) {
        int n = n0 + wn + nt * 16 + l16;
        float bv = bias[n];
        if (VFUSE && n >= 2048) {
            int d = n & 63, h = (n - 2048) >> 6;
#pragma unroll
            for (int mt = 0; mt < MT; ++mt) {
                int m = m0 + wm + mt * 16 + quad * 4;
                int b = m >> 11, sidx = m & 2047;
                bf16x4 pk;
#pragma unroll
                for (int r = 0; r < 4; ++r) pk[r] = (bf16)(acc[mt][nt][r] + bv);
                *(bf16x4*)(vT + (((size_t)(b * 16 + h) * 64 + d) * SEQ + sidx)) = pk;
            }
        } else {
#pragma unroll
            for (int mt = 0; mt < MT; ++mt) {
#pragma unroll
                for (int r = 0; r < 4; ++r) {
                    int m = m0 + wm + mt * 16 + quad * 4 + r;
                    float vv = acc[mt][nt][r] + bv;
                    if (Rb) vv += (float)Rb[(size_t)m * N + n];
                    if (Rf) vv += Rf[(size_t)m * N + n];
                    if (relu) vv = vv > 0.0f ? vv : 0.0f;
                    C[(size_t)m * N + n] = (OutT)vv;
                }
            }
        }
    }
}

// ---------------- Flash attention, dh=64, fixed-max softmax ----------------
// grid: (SEQ/128, 32 bh), block 512 = 4 q-groups (32 q) x 2 key-groups.
// K double-buffered in LDS, ONE barrier/tile. V is NOT staged in LDS:
// per-bh V working set (256 KB) is L2-resident, and each wave's V fragments
// are read directly from global (4x global_load_dwordx4, ~200cy L2 latency
// hidden under the K ds_reads + 8 QK MFMAs + exp chain before PV consumes
// them). This removes the V prefetch regs, the V stage ds_write, and 4
// ds_read_b128 per wave-iter (-1/3 of LDS issue + Vt bank conflicts).
// LDS 57344 -> 38912. Numerics identical to the staged version.
__global__ __launch_bounds__(512) void attn_kernel(
    const bf16* __restrict__ qkv, const bf16* __restrict__ vT, bf16* __restrict__ O)
{
    __shared__ __align__(16) char smem[38912];
    // K buf b at smem + b*9216: Ks [64 keys][72]
    bf16* Ps = (bf16*)(smem + 18432);    // [8 waves][32 q][40 keys-padded]

    int tid = threadIdx.x;
    int wave = tid >> 6, lane = tid & 63;
    int quad = lane >> 4, l16 = lane & 15;
    int qg = wave >> 1, kg = wave & 1;
    int bh = blockIdx.y, b = bh >> 4, h = bh & 15;
    int q0 = blockIdx.x * 128 + qg * 32;

    const bf16* Qb = qkv + (size_t)(b * SEQ + q0) * 3072 + h * 64;
    const bf16* Kb = qkv + (size_t)(b * SEQ) * 3072 + 1024 + h * 64;
    const bf16* Vb = vT + (size_t)bh * 64 * SEQ;

    const float c_l2 = 0.125f * LOG2E;
    bf16x8 qa[2][2];
#pragma unroll
    for (int mt = 0; mt < 2; ++mt)
#pragma unroll
        for (int hf = 0; hf < 2; ++hf) {
            bf16x8 raw = *(const bf16x8*)(Qb + (size_t)(mt * 16 + l16) * 3072 + hf * 32 + quad * 8);
            bf16x8 sc;
#pragma unroll
            for (int j = 0; j < 8; ++j) sc[j] = (bf16)((float)raw[j] * c_l2);
            qa[mt][hf] = sc;
        }

    float lsum[2] = {};
    f32x4 oacc[2][4] = {};

    int sr = tid >> 3, scol = (tid & 7) * 8;   // 64 rows x 8 chunks (512 thr)
    const bf16* kp = Kb + (size_t)sr * 3072 + scol;
    bf16x8 kr = *(const bf16x8*)kp;

    // per-thread V base: row d = dt*16 + l16, key col = kg*32 + quad*8
    const bf16* vptr = Vb + (size_t)l16 * SEQ + kg * 32 + quad * 8;

    bf16* PsW = Ps + wave * 32 * 40;

    // prologue: stage K tile 0 into buf0; prefetch K tile 1 into regs
    {
        bf16* K0 = (bf16*)smem;
        *(bf16x8*)(K0 + sr * 72 + scol) = kr;
    }
    kr = *(const bf16x8*)(kp + (size_t)64 * 3072);
    __syncthreads();

    for (int kt = 0; kt < SEQ; kt += 64) {
        int cur = (kt >> 6) & 1;
        bf16* Ks = (bf16*)(smem + cur * 9216);
        const bf16* KsKg = Ks + kg * 32 * 72;

        // stage NEXT K tile into the other buffer (overlaps this tile's compute)
        if (kt + 64 < SEQ) {
            bf16* Kn = (bf16*)(smem + (cur ^ 1) * 9216);
            *(bf16x8*)(Kn + sr * 72 + scol) = kr;
        }
        // prefetch K tile after next into regs
        if (kt + 128 < SEQ) {
            kr = *(const bf16x8*)(kp + (size_t)(kt + 128) * 3072);
        }

        // V fragments straight from global (L2-resident); issue early so the
        // latency hides under kb ds_reads + QK MFMAs + exp.
        bf16x8 vb[4];
#pragma unroll
        for (int dt = 0; dt < 4; ++dt)
            vb[dt] = *(const bf16x8*)(vptr + (size_t)(dt * 16) * SEQ + kt);

        bf16x8 kb[2][2];
#pragma unroll
        for (int t4 = 0; t4 < 2; ++t4) {
            kb[t4][0] = *(const bf16x8*)(KsKg + (t4 * 16 + l16) * 72 + quad * 8);
            kb[t4][1] = *(const bf16x8*)(KsKg + (t4 * 16 + l16) * 72 + 32 + quad * 8);
        }

        // S^T over this wave's 32 keys: rows = keys, col = q (l16)
#pragma unroll
        for (int mt = 0; mt < 2; ++mt)
#pragma unroll
            for (int t4 = 0; t4 < 2; ++t4) {
                f32x4 c = {};
                c = __builtin_amdgcn_mfma_f32_16x16x32_bf16(kb[t4][0], qa[mt][0], c, 0, 0, 0);
                c = __builtin_amdgcn_mfma_f32_16x16x32_bf16(kb[t4][1], qa[mt][1], c, 0, 0, 0);
                bf16x4 pk;
                float psum = 0.0f;
#pragma unroll
                for (int r = 0; r < 4; ++r) {
                    float p = exp2f(c[r]);
                    psum += p;
                    pk[r] = (bf16)p;
                }
                lsum[mt] += psum;
                *(bf16x4*)(PsW + (mt * 16 + l16) * 40 + t4 * 16 + quad * 4) = pk;
            }
        // PV over this wave's 32 keys (K=32 mfma)
#pragma unroll
        for (int mt = 0; mt < 2; ++mt) {
            bf16x8 pa = *(const bf16x8*)(PsW + (mt * 16 + l16) * 40 + quad * 8);
#pragma unroll
            for (int dt = 0; dt < 4; ++dt)
                oacc[mt][dt] = __builtin_amdgcn_mfma_f32_16x16x32_bf16(pa, vb[dt], oacc[mt][dt], 0, 0, 0);
        }

        __syncthreads();   // single barrier per tile (K staging only)
    }

    // cross-quad lsum reduce (per q = mt*16 + l16)
    float lr[2];
#pragma unroll
    for (int mt = 0; mt < 2; ++mt) {
        lr[mt] = lsum[mt];
        lr[mt] += __shfl_xor(lr[mt], 16);
        lr[mt] += __shfl_xor(lr[mt], 32);
    }
    // merge the two key-groups via LDS (K bufs + Ps dead; 32KB sf + 1KB lb
    // fit in the 38912B block)
    float* sf = (float*)smem;                  // [qg][d 64][q 32] = 32 KB
    float* lb = sf + 8192;                     // [qg][mt][16]
    if (kg == 1) {
#pragma unroll
        for (int mt = 0; mt < 2; ++mt)
#pragma unroll
            for (int dt = 0; dt < 4; ++dt)
                *(f32x4*)&sf[qg * 2048 + (dt * 16 + l16) * 32 + mt * 16 + quad * 4] = oacc[mt][dt];
        if (lane < 16) {
            lb[(qg * 2 + 0) * 16 + l16] = lr[0];
            lb[(qg * 2 + 1) * 16 + l16] = lr[1];
        }
    }
    __syncthreads();
    if (kg == 0) {
#pragma unroll
        for (int mt = 0; mt < 2; ++mt) {
            lr[mt] += lb[(qg * 2 + mt) * 16 + l16];
#pragma unroll
            for (int dt = 0; dt < 4; ++dt) {
                f32x4 other = *(const f32x4*)&sf[qg * 2048 + (dt * 16 + l16) * 32 + mt * 16 + quad * 4];
                oacc[mt][dt] += other;
            }
        }
#pragma unroll
        for (int mt = 0; mt < 2; ++mt)
#pragma unroll
            for (int r = 0; r < 4; ++r) {
                float inv = 1.0f / __shfl(lr[mt], quad * 4 + r, 16);
                int row = b * SEQ + q0 + mt * 16 + quad * 4 + r;
                bf16* op = O + (size_t)row * D_MODEL + h * 64;
#pragma unroll
                for (int dt = 0; dt < 4; ++dt)
                    op[dt * 16 + l16] = (bf16)(oacc[mt][dt][r] * inv);
            }
    }
}

// ---------------- launch ----------------
extern "C" void kernel_launch(void* const* d_in, const int* in_sizes, int n_in,
                              void* d_out, int out_size, void* d_ws, size_t ws_size,
                              hipStream_t stream)
{
    const float* x      = (const float*)d_in[0];
    const float* Wq     = (const float*)d_in[1];
    const float* bq     = (const float*)d_in[2];
    const float* Wk     = (const float*)d_in[3];
    const float* bk     = (const float*)d_in[4];
    const float* Wv     = (const float*)d_in[5];
    const float* bv     = (const float*)d_in[6];
    const float* Wo     = (const float*)d_in[7];
    const float* bo     = (const float*)d_in[8];
    const float* alpha1 = (const float*)d_in[9];
    const float* beta1  = (const float*)d_in[10];
    const float* alpha2 = (const float*)d_in[11];
    const float* beta2  = (const float*)d_in[12];
    const float* W1     = (const float*)d_in[13];
    const float* b1     = (const float*)d_in[14];
    const float* W2     = (const float*)d_in[15];
    const float* b2     = (const float*)d_in[16];

    char* ws = (char*)d_ws;
    const size_t MB = 1ull << 20;
    bf16*  Wqkv_t = (bf16*)(ws + 0 * MB);    // 6 MB
    bf16*  Wo_t   = (bf16*)(ws + 6 * MB);    // 2 MB
    bf16*  W1_t   = (bf16*)(ws + 8 * MB);    // 1 MB
    bf16*  W2_t   = (bf16*)(ws + 9 * MB);    // 1 MB
    float* b_qkv  = (float*)(ws + 10 * MB);
    bf16*  xn     = (bf16*)(ws + 11 * MB);   // 8 MB (live until Wo epilogue)
    bf16*  qkv    = (bf16*)(ws + 19 * MB);   // 24 MB (q,k live until attn)
    bf16*  vT     = (bf16*)(ws + 43 * MB);   // 8 MB (dead after attn)
    bf16*  o      = (bf16*)(ws + 51 * MB);   // 8 MB (dead after Wo)
    float* x2     = (float*)(ws + 19 * MB);  // fp32 16 MB over dead qkv head
    bf16*  hn     = (bf16*)(ws + 35 * MB);   // 8 MB over dead qkv tail
    bf16*  h1     = (bf16*)(ws + 11 * MB);   // 4 MB over dead xn

    const int M = NB * SEQ;

    prep_norm_kernel<<<4096 + 1292, 256, 0, stream>>>(
        x, alpha1, beta1, xn, Wq, Wk, Wv, Wo, W1, W2, bq, bk, bv,
        Wqkv_t, Wo_t, W1_t, W2_t, b_qkv);

    // fused QKV GEMM, BM=128/KU=2 (proven 3 blocks/CU), V written transposed
    gemm128<bf16, 128, 128, 2, true><<<dim3(24, 32), 256, 0, stream>>>(
        xn, Wqkv_t, b_qkv, nullptr, nullptr, qkv, vT, M, 3072, D_MODEL, D_MODEL, 0);

    attn_kernel<<<dim3(SEQ / 128, 32), 512, 0, stream>>>(qkv, vT, o);

    // x2 = xn + o @ Wo + bo  (BM=64: 1024 blocks = 4/CU)
    gemm128<float, 64, 64, 4, false><<<dim3(16, 64), 256, 0, stream>>>(
        o, Wo_t, bo, xn, nullptr, x2, nullptr, M, D_MODEL, D_MODEL, D_MODEL, 0);

    norm_kernel<<<M, 256, 0, stream>>>(x2, alpha2, beta2, hn);

    // FFN1: h1 = relu(hn @ W1 + b1), BM=64/BN=32: 1024 blocks = 4/CU
    gemm128<bf16, 64, 32, 4, false><<<dim3(16, 64), 256, 0, stream>>>(
        hn, W1_t, b1, nullptr, nullptr, h1, nullptr, M, 512, D_MODEL, D_MODEL, 1);

    // out = x2 + h1 @ W2 + b2  (BM=64: 1024 blocks = 4/CU)
    gemm128<float, 64, 64, 4, false><<<dim3(16, 64), 256, 0, stream>>>(
        h1, W2_t, b2, nullptr, x2, (float*)d_out, nullptr, M, D_MODEL, 512, 512, 0);
}

// Round 12
// 267.807 us; speedup vs baseline: 1.0621x; 1.0621x over previous
//
#include <hip/hip_runtime.h>

typedef __bf16 bf16;
typedef __bf16 bf16x4 __attribute__((ext_vector_type(4)));
typedef __bf16 bf16x8 __attribute__((ext_vector_type(8)));
typedef float f32x4 __attribute__((ext_vector_type(4)));

#define D_MODEL 1024
#define SEQ 2048
#define NB 2
#define LOG2E 1.4426950408889634f

// async global->LDS, 16B per lane; LDS dest = wave-uniform base + lane*16
__device__ __forceinline__ void glds16(const bf16* g, bf16* l) {
    __builtin_amdgcn_global_load_lds(
        (const __attribute__((address_space(1))) void*)g,
        (__attribute__((address_space(3))) void*)l, 16, 0, 0);
}

// ---------------- fused prep (weights W^T + bias concat) + norm1 ----------------
__device__ __forceinline__ void tile_tcvt(
    const float* __restrict__ src, int rows, int cols, bf16* __restrict__ dst,
    int bx, int by, bf16 (*t)[72])
{
    int tid = threadIdx.x;
    int k0 = by * 64, n0 = bx * 64;
    int r = tid >> 2, c = (tid & 3) * 16;
    const float4* s = (const float4*)(src + (size_t)(k0 + r) * cols + n0 + c);
#pragma unroll
    for (int q = 0; q < 4; ++q) {
        float4 v = s[q];
        t[c + q * 4 + 0][r] = (bf16)v.x;
        t[c + q * 4 + 1][r] = (bf16)v.y;
        t[c + q * 4 + 2][r] = (bf16)v.z;
        t[c + q * 4 + 3][r] = (bf16)v.w;
    }
    __syncthreads();
    bf16* d = dst + (size_t)(n0 + r) * rows + k0 + c;
    *(bf16x8*)(d)     = *(const bf16x8*)&t[r][c];
    *(bf16x8*)(d + 8) = *(const bf16x8*)&t[r][c + 8];
}

__device__ __forceinline__ void norm_row(
    const float* __restrict__ X, const float* __restrict__ alpha,
    const float* __restrict__ beta, bf16* __restrict__ Y, int row)
{
    int tid = threadIdx.x;
    float4 v = ((const float4*)(X + (size_t)row * D_MODEL))[tid];
    float s = v.x + v.y + v.z + v.w;
    float ss = v.x*v.x + v.y*v.y + v.z*v.z + v.w*v.w;
#pragma unroll
    for (int off = 1; off < 64; off <<= 1) {
        s  += __shfl_xor(s, off, 64);
        ss += __shfl_xor(ss, off, 64);
    }
    __shared__ float sd[8];
    int wave = tid >> 6, lane = tid & 63;
    if (lane == 0) { sd[wave] = s; sd[4 + wave] = ss; }
    __syncthreads();
    s  = sd[0] + sd[1] + sd[2] + sd[3];
    ss = sd[4] + sd[5] + sd[6] + sd[7];
    float mean = s * (1.0f / 1024.0f);
    float var  = (ss - s * mean) * (1.0f / 1023.0f);
    float rs = rsqrtf(var + 1e-6f);
    float4 a = ((const float4*)alpha)[tid];
    float4 bt = ((const float4*)beta)[tid];
    bf16x4 o;
    o[0] = (bf16)(a.x * (v.x - mean) * rs + bt.x);
    o[1] = (bf16)(a.y * (v.y - mean) * rs + bt.y);
    o[2] = (bf16)(a.z * (v.z - mean) * rs + bt.z);
    o[3] = (bf16)(a.w * (v.w - mean) * rs + bt.w);
    *(bf16x4*)(Y + (size_t)row * D_MODEL + tid * 4) = o;
}

__global__ __launch_bounds__(256) void prep_norm_kernel(
    const float* __restrict__ x, const float* __restrict__ alpha1,
    const float* __restrict__ beta1, bf16* __restrict__ xn,
    const float* __restrict__ Wq, const float* __restrict__ Wk,
    const float* __restrict__ Wv, const float* __restrict__ Wo,
    const float* __restrict__ W1, const float* __restrict__ W2,
    const float* __restrict__ bq, const float* __restrict__ bk,
    const float* __restrict__ bv,
    bf16* __restrict__ Wqkv_t, bf16* __restrict__ Wo_t,
    bf16* __restrict__ W1_t, bf16* __restrict__ W2_t,
    float* __restrict__ b_qkv)
{
    __shared__ bf16 t[64][72];
    int id = blockIdx.x;
    if (id < 4096) {
        norm_row(x, alpha1, beta1, xn, id);
        return;
    }
    id -= 4096;
    if (id < 1024) {
        int which = id >> 8, tile = id & 255;
        const float* src = which == 0 ? Wq : which == 1 ? Wk : which == 2 ? Wv : Wo;
        bf16* dst = which == 3 ? Wo_t : Wqkv_t + (size_t)which * 1024 * 1024;
        tile_tcvt(src, 1024, 1024, dst, tile & 15, tile >> 4, t);
    } else if (id < 1152) {
        int tile = id - 1024;
        tile_tcvt(W1, 1024, 512, W1_t, tile & 7, tile >> 3, t);
    } else if (id < 1280) {
        int tile = id - 1152;
        tile_tcvt(W2, 512, 1024, W2_t, tile & 15, tile >> 4, t);
    } else {
        int i = (id - 1280) * 256 + threadIdx.x;
        float v;
        if (i < 1024) v = bq[i];
        else if (i < 2048) v = bk[i - 1024];
        else v = bv[i - 2048];
        b_qkv[i] = v;
    }
}

// ---------------- LayerNorm standalone (norm2) ----------------
__global__ __launch_bounds__(256) void norm_kernel(
    const float* __restrict__ X, const float* __restrict__ alpha,
    const float* __restrict__ beta, bf16* __restrict__ Y)
{
    norm_row(X, alpha, beta, Y, blockIdx.x);
}

// ---------------- GEMM: C = A(MxK,lda)@Bt^T + bias [+Rb/+Rf] [ReLU] ----------------
// Tile BM x BN, K-step 32*KU, 4 waves (2x2), mfma 16x16x32.
// BM=64: halves per-block work -> doubles grid (occupancy fix; R10 proved
// 2->4 blocks/CU on the small GEMMs, applied to QKV here for 3->6).
// BN=32: B-tile staged by first 128 threads only (wave-uniform guard).
// VFUSE: n>=2048 columns (V proj) written transposed into vT[bh][d][s].
template <typename OutT, int BM, int BN, int KU, bool VFUSE>
__global__ __launch_bounds__(256) void gemm128(
    const bf16* __restrict__ A, const bf16* __restrict__ Bt,
    const float* __restrict__ bias, const bf16* __restrict__ Rb,
    const float* __restrict__ Rf, OutT* __restrict__ C, bf16* __restrict__ vT,
    int M, int N, int K, int lda, int relu)
{
    constexpr int MT = BM / 32;
    constexpr int NT = BN / 32;
    constexpr int ASTR = BM * 32;
    constexpr int BSTR = BN * 32;
    __shared__ bf16 As[ASTR * KU];
    __shared__ bf16 Bs[BSTR * KU];

    int tid = threadIdx.x;
    int wave = tid >> 6, lane = tid & 63;
    int quad = lane >> 4, l16 = lane & 15;
    int m0 = blockIdx.y * BM, n0 = blockIdx.x * BN;
    int wm = (wave >> 1) * (BM / 2), wn = (wave & 1) * (BN / 2);

    f32x4 acc[MT][NT] = {};

    const bf16* ga = A  + (size_t)(m0 + (tid >> 2)) * lda + (tid & 3) * 8;
    const bf16* gb = Bt + (size_t)(n0 + (tid >> 2)) * K   + (tid & 3) * 8;
    bf16* lAs = As + wave * 512;
    bf16* lBs = Bs + wave * 512;

    for (int k0 = 0; k0 < K; k0 += 32 * KU) {
        __syncthreads();
#pragma unroll
        for (int u = 0; u < KU; ++u) {
            glds16(ga + k0 + u * 32, lAs + u * ASTR);
            if (BM == 128)
                glds16(ga + (size_t)64 * lda + k0 + u * 32, lAs + u * ASTR + 2048);
            if (BN >= 64 || tid < 128)
                glds16(gb + k0 + u * 32, lBs + u * BSTR);
            if (BN == 128) glds16(gb + (size_t)64 * K + k0 + u * 32, lBs + u * BSTR + 2048);
        }
        __syncthreads();
#pragma unroll
        for (int u = 0; u < KU; ++u) {
            bf16x8 af[MT], bfr[NT];
#pragma unroll
            for (int mt = 0; mt < MT; ++mt)
                af[mt] = *(const bf16x8*)(As + u * ASTR + (wm + mt * 16 + l16) * 32 + quad * 8);
#pragma unroll
            for (int nt = 0; nt < NT; ++nt)
                bfr[nt] = *(const bf16x8*)(Bs + u * BSTR + (wn + nt * 16 + l16) * 32 + quad * 8);
#pragma unroll
            for (int mt = 0; mt < MT; ++mt)
#pragma unroll
                for (int nt = 0; nt < NT; ++nt)
                    acc[mt][nt] = __builtin_amdgcn_mfma_f32_16x16x32_bf16(af[mt], bfr[nt], acc[mt][nt], 0, 0, 0);
        }
    }

#pragma unroll
    for (int nt = 0; nt < NT; ++nt) {
        int n = n0 + wn + nt * 16 + l16;
        float bv = bias[n];
        if (VFUSE && n >= 2048) {
            int d = n & 63, h = (n - 2048) >> 6;
#pragma unroll
            for (int mt = 0; mt < MT; ++mt) {
                int m = m0 + wm + mt * 16 + quad * 4;
                int b = m >> 11, sidx = m & 2047;
                bf16x4 pk;
#pragma unroll
                for (int r = 0; r < 4; ++r) pk[r] = (bf16)(acc[mt][nt][r] + bv);
                *(bf16x4*)(vT + (((size_t)(b * 16 + h) * 64 + d) * SEQ + sidx)) = pk;
            }
        } else {
#pragma unroll
            for (int mt = 0; mt < MT; ++mt) {
#pragma unroll
                for (int r = 0; r < 4; ++r) {
                    int m = m0 + wm + mt * 16 + quad * 4 + r;
                    float vv = acc[mt][nt][r] + bv;
                    if (Rb) vv += (float)Rb[(size_t)m * N + n];
                    if (Rf) vv += Rf[(size_t)m * N + n];
                    if (relu) vv = vv > 0.0f ? vv : 0.0f;
                    C[(size_t)m * N + n] = (OutT)vv;
                }
            }
        }
    }
}

// ---------------- Flash attention, dh=64, fixed-max softmax ----------------
// CLOSED at the R6/R10 variant (64.9 us measured): S^T QK -> Ps LDS buffer
// -> PV, K/V double-buffered in LDS, ONE barrier/tile, 2 blocks/CU.
// Tried and rejected: split-K (R1, occupancy-capped elsewhere), in-register
// permlane P (R2, serial VALU chain), K=16 PV (R4, 2x pipe cost), cross-tile
// pipeline (R7/R8, +12 VGPR -> 1 block/CU), V-unstaging (R11, 2x V traffic
// + exposed L2 latency).
__global__ __launch_bounds__(512) void attn_kernel(
    const bf16* __restrict__ qkv, const bf16* __restrict__ vT, bf16* __restrict__ O)
{
    __shared__ __align__(16) char smem[57344];
    // buf b at smem + b*18432: Ks [64][72] then Vt [64][72]
    bf16* Ps = (bf16*)(smem + 36864);    // [8 waves][32 q][40 keys-padded]

    int tid = threadIdx.x;
    int wave = tid >> 6, lane = tid & 63;
    int quad = lane >> 4, l16 = lane & 15;
    int qg = wave >> 1, kg = wave & 1;
    int bh = blockIdx.y, b = bh >> 4, h = bh & 15;
    int q0 = blockIdx.x * 128 + qg * 32;

    const bf16* Qb = qkv + (size_t)(b * SEQ + q0) * 3072 + h * 64;
    const bf16* Kb = qkv + (size_t)(b * SEQ) * 3072 + 1024 + h * 64;
    const bf16* Vb = vT + (size_t)bh * 64 * SEQ;

    const float c_l2 = 0.125f * LOG2E;
    bf16x8 qa[2][2];
#pragma unroll
    for (int mt = 0; mt < 2; ++mt)
#pragma unroll
        for (int hf = 0; hf < 2; ++hf) {
            bf16x8 raw = *(const bf16x8*)(Qb + (size_t)(mt * 16 + l16) * 3072 + hf * 32 + quad * 8);
            bf16x8 sc;
#pragma unroll
            for (int j = 0; j < 8; ++j) sc[j] = (bf16)((float)raw[j] * c_l2);
            qa[mt][hf] = sc;
        }

    float lsum[2] = {};
    f32x4 oacc[2][4] = {};

    int sr = tid >> 3, scol = (tid & 7) * 8;   // 64 rows x 8 chunks (512 thr)
    const bf16* kp = Kb + (size_t)sr * 3072 + scol;
    const bf16* vp = Vb + (size_t)sr * SEQ + scol;
    bf16x8 kr = *(const bf16x8*)kp;
    bf16x8 vr = *(const bf16x8*)vp;

    bf16* PsW = Ps + wave * 32 * 40;

    // prologue: stage tile 0 into buf0; prefetch tile 1 into regs
    {
        bf16* K0 = (bf16*)smem;
        *(bf16x8*)(K0 + sr * 72 + scol) = kr;
        *(bf16x8*)(K0 + 4608 + sr * 72 + scol) = vr;
    }
    kr = *(const bf16x8*)(kp + (size_t)64 * 3072);
    vr = *(const bf16x8*)(vp + 64);
    __syncthreads();

    for (int kt = 0; kt < SEQ; kt += 64) {
        int cur = (kt >> 6) & 1;
        bf16* Ks = (bf16*)(smem + cur * 18432);
        bf16* Vt = Ks + 4608;
        const bf16* KsKg = Ks + kg * 32 * 72;

        // stage NEXT tile into the other buffer (overlaps this tile's compute)
        if (kt + 64 < SEQ) {
            bf16* Kn = (bf16*)(smem + (cur ^ 1) * 18432);
            *(bf16x8*)(Kn + sr * 72 + scol) = kr;
            *(bf16x8*)(Kn + 4608 + sr * 72 + scol) = vr;
        }
        // prefetch tile after next into regs (HBM latency hides under compute)
        if (kt + 128 < SEQ) {
            kr = *(const bf16x8*)(kp + (size_t)(kt + 128) * 3072);
            vr = *(const bf16x8*)(vp + kt + 128);
        }

        bf16x8 kb[2][2], vb[4];
#pragma unroll
        for (int t4 = 0; t4 < 2; ++t4) {
            kb[t4][0] = *(const bf16x8*)(KsKg + (t4 * 16 + l16) * 72 + quad * 8);
            kb[t4][1] = *(const bf16x8*)(KsKg + (t4 * 16 + l16) * 72 + 32 + quad * 8);
        }
#pragma unroll
        for (int dt = 0; dt < 4; ++dt)
            vb[dt] = *(const bf16x8*)(Vt + (dt * 16 + l16) * 72 + kg * 32 + quad * 8);

        // S^T over this wave's 32 keys: rows = keys, col = q (l16)
#pragma unroll
        for (int mt = 0; mt < 2; ++mt)
#pragma unroll
            for (int t4 = 0; t4 < 2; ++t4) {
                f32x4 c = {};
                c = __builtin_amdgcn_mfma_f32_16x16x32_bf16(kb[t4][0], qa[mt][0], c, 0, 0, 0);
                c = __builtin_amdgcn_mfma_f32_16x16x32_bf16(kb[t4][1], qa[mt][1], c, 0, 0, 0);
                bf16x4 pk;
                float psum = 0.0f;
#pragma unroll
                for (int r = 0; r < 4; ++r) {
                    float p = exp2f(c[r]);
                    psum += p;
                    pk[r] = (bf16)p;
                }
                lsum[mt] += psum;
                *(bf16x4*)(PsW + (mt * 16 + l16) * 40 + t4 * 16 + quad * 4) = pk;
            }
        // PV over this wave's 32 keys (K=32 mfma)
#pragma unroll
        for (int mt = 0; mt < 2; ++mt) {
            bf16x8 pa = *(const bf16x8*)(PsW + (mt * 16 + l16) * 40 + quad * 8);
#pragma unroll
            for (int dt = 0; dt < 4; ++dt)
                oacc[mt][dt] = __builtin_amdgcn_mfma_f32_16x16x32_bf16(pa, vb[dt], oacc[mt][dt], 0, 0, 0);
        }

        __syncthreads();   // single barrier per tile
    }

    // cross-quad lsum reduce (per q = mt*16 + l16)
    float lr[2];
#pragma unroll
    for (int mt = 0; mt < 2; ++mt) {
        lr[mt] = lsum[mt];
        lr[mt] += __shfl_xor(lr[mt], 16);
        lr[mt] += __shfl_xor(lr[mt], 32);
    }
    // merge the two key-groups via LDS (Ks/Vt/Ps dead now; loop barrier passed)
    float* sf = (float*)smem;                  // [qg][d 64][q 32]
    float* lb = sf + 8192;                     // [qg][mt][16]
    if (kg == 1) {
#pragma unroll
        for (int mt = 0; mt < 2; ++mt)
#pragma unroll
            for (int dt = 0; dt < 4; ++dt)
                *(f32x4*)&sf[qg * 2048 + (dt * 16 + l16) * 32 + mt * 16 + quad * 4] = oacc[mt][dt];
        if (lane < 16) {
            lb[(qg * 2 + 0) * 16 + l16] = lr[0];
            lb[(qg * 2 + 1) * 16 + l16] = lr[1];
        }
    }
    __syncthreads();
    if (kg == 0) {
#pragma unroll
        for (int mt = 0; mt < 2; ++mt) {
            lr[mt] += lb[(qg * 2 + mt) * 16 + l16];
#pragma unroll
            for (int dt = 0; dt < 4; ++dt) {
                f32x4 other = *(const f32x4*)&sf[qg * 2048 + (dt * 16 + l16) * 32 + mt * 16 + quad * 4];
                oacc[mt][dt] += other;
            }
        }
#pragma unroll
        for (int mt = 0; mt < 2; ++mt)
#pragma unroll
            for (int r = 0; r < 4; ++r) {
                float inv = 1.0f / __shfl(lr[mt], quad * 4 + r, 16);
                int row = b * SEQ + q0 + mt * 16 + quad * 4 + r;
                bf16* op = O + (size_t)row * D_MODEL + h * 64;
#pragma unroll
                for (int dt = 0; dt < 4; ++dt)
                    op[dt * 16 + l16] = (bf16)(oacc[mt][dt][r] * inv);
            }
    }
}

// ---------------- launch ----------------
extern "C" void kernel_launch(void* const* d_in, const int* in_sizes, int n_in,
                              void* d_out, int out_size, void* d_ws, size_t ws_size,
                              hipStream_t stream)
{
    const float* x      = (const float*)d_in[0];
    const float* Wq     = (const float*)d_in[1];
    const float* bq     = (const float*)d_in[2];
    const float* Wk     = (const float*)d_in[3];
    const float* bk     = (const float*)d_in[4];
    const float* Wv     = (const float*)d_in[5];
    const float* bv     = (const float*)d_in[6];
    const float* Wo     = (const float*)d_in[7];
    const float* bo     = (const float*)d_in[8];
    const float* alpha1 = (const float*)d_in[9];
    const float* beta1  = (const float*)d_in[10];
    const float* alpha2 = (const float*)d_in[11];
    const float* beta2  = (const float*)d_in[12];
    const float* W1     = (const float*)d_in[13];
    const float* b1     = (const float*)d_in[14];
    const float* W2     = (const float*)d_in[15];
    const float* b2     = (const float*)d_in[16];

    char* ws = (char*)d_ws;
    const size_t MB = 1ull << 20;
    bf16*  Wqkv_t = (bf16*)(ws + 0 * MB);    // 6 MB
    bf16*  Wo_t   = (bf16*)(ws + 6 * MB);    // 2 MB
    bf16*  W1_t   = (bf16*)(ws + 8 * MB);    // 1 MB
    bf16*  W2_t   = (bf16*)(ws + 9 * MB);    // 1 MB
    float* b_qkv  = (float*)(ws + 10 * MB);
    bf16*  xn     = (bf16*)(ws + 11 * MB);   // 8 MB (live until Wo epilogue)
    bf16*  qkv    = (bf16*)(ws + 19 * MB);   // 24 MB (q,k live until attn)
    bf16*  vT     = (bf16*)(ws + 43 * MB);   // 8 MB (dead after attn)
    bf16*  o      = (bf16*)(ws + 51 * MB);   // 8 MB (dead after Wo)
    float* x2     = (float*)(ws + 19 * MB);  // fp32 16 MB over dead qkv head
    bf16*  hn     = (bf16*)(ws + 35 * MB);   // 8 MB over dead qkv tail
    bf16*  h1     = (bf16*)(ws + 11 * MB);   // 4 MB over dead xn

    const int M = NB * SEQ;

    prep_norm_kernel<<<4096 + 1292, 256, 0, stream>>>(
        x, alpha1, beta1, xn, Wq, Wk, Wv, Wo, W1, W2, bq, bk, bv,
        Wqkv_t, Wo_t, W1_t, W2_t, b_qkv);

    // fused QKV GEMM, BM=64/KU=2: grid (24,64) = 1536 blocks = 6 blocks/CU
    // (was BM=128 at 768 = 3/CU, 37.5% occupancy grid-capped). Same HBM
    // traffic (xn + Wqkv_t are L3-resident); 2x the latency-hiding waves.
    gemm128<bf16, 64, 128, 2, true><<<dim3(24, 64), 256, 0, stream>>>(
        xn, Wqkv_t, b_qkv, nullptr, nullptr, qkv, vT, M, 3072, D_MODEL, D_MODEL, 0);

    attn_kernel<<<dim3(SEQ / 128, 32), 512, 0, stream>>>(qkv, vT, o);

    // x2 = xn + o @ Wo + bo  (BM=64: 1024 blocks = 4/CU)
    gemm128<float, 64, 64, 4, false><<<dim3(16, 64), 256, 0, stream>>>(
        o, Wo_t, bo, xn, nullptr, x2, nullptr, M, D_MODEL, D_MODEL, D_MODEL, 0);

    norm_kernel<<<M, 256, 0, stream>>>(x2, alpha2, beta2, hn);

    // FFN1: h1 = relu(hn @ W1 + b1), BM=64/BN=32: 1024 blocks = 4/CU
    gemm128<bf16, 64, 32, 4, false><<<dim3(16, 64), 256, 0, stream>>>(
        hn, W1_t, b1, nullptr, nullptr, h1, nullptr, M, 512, D_MODEL, D_MODEL, 1);

    // out = x2 + h1 @ W2 + b2  (BM=64: 1024 blocks = 4/CU)
    gemm128<float, 64, 64, 4, false><<<dim3(16, 64), 256, 0, stream>>>(
        h1, W2_t, b2, nullptr, x2, (float*)d_out, nullptr, M, D_MODEL, 512, 512, 0);
}

// Round 14
// 261.976 us; speedup vs baseline: 1.0858x; 1.0223x over previous
//
#include <hip/hip_runtime.h>

typedef __bf16 bf16;
typedef __bf16 bf16x4 __attribute__((ext_vector_type(4)));
typedef __bf16 bf16x8 __attribute__((ext_vector_type(8)));
typedef float f32x4 __attribute__((ext_vector_type(4)));

#define D_MODEL 1024
#define SEQ 2048
#define NB 2
#define LOG2E 1.4426950408889634f

// async global->LDS, 16B per lane; LDS dest = wave-uniform base + lane*16
__device__ __forceinline__ void glds16(const bf16* g, bf16* l) {
    __builtin_amdgcn_global_load_lds(
        (const __attribute__((address_space(1))) void*)g,
        (__attribute__((address_space(3))) void*)l, 16, 0, 0);
}

// ---------------- fused prep (weights W^T + bias concat) + norm1 ----------------
__device__ __forceinline__ void tile_tcvt(
    const float* __restrict__ src, int rows, int cols, bf16* __restrict__ dst,
    int bx, int by, bf16 (*t)[72])
{
    int tid = threadIdx.x;
    int k0 = by * 64, n0 = bx * 64;
    int r = tid >> 2, c = (tid & 3) * 16;
    const float4* s = (const float4*)(src + (size_t)(k0 + r) * cols + n0 + c);
#pragma unroll
    for (int q = 0; q < 4; ++q) {
        float4 v = s[q];
        t[c + q * 4 + 0][r] = (bf16)v.x;
        t[c + q * 4 + 1][r] = (bf16)v.y;
        t[c + q * 4 + 2][r] = (bf16)v.z;
        t[c + q * 4 + 3][r] = (bf16)v.w;
    }
    __syncthreads();
    bf16* d = dst + (size_t)(n0 + r) * rows + k0 + c;
    *(bf16x8*)(d)     = *(const bf16x8*)&t[r][c];
    *(bf16x8*)(d + 8) = *(const bf16x8*)&t[r][c + 8];
}

__device__ __forceinline__ void norm_row(
    const float* __restrict__ X, const float* __restrict__ alpha,
    const float* __restrict__ beta, bf16* __restrict__ Y, int row)
{
    int tid = threadIdx.x;
    float4 v = ((const float4*)(X + (size_t)row * D_MODEL))[tid];
    float s = v.x + v.y + v.z + v.w;
    float ss = v.x*v.x + v.y*v.y + v.z*v.z + v.w*v.w;
#pragma unroll
    for (int off = 1; off < 64; off <<= 1) {
        s  += __shfl_xor(s, off, 64);
        ss += __shfl_xor(ss, off, 64);
    }
    __shared__ float sd[8];
    int wave = tid >> 6, lane = tid & 63;
    if (lane == 0) { sd[wave] = s; sd[4 + wave] = ss; }
    __syncthreads();
    s  = sd[0] + sd[1] + sd[2] + sd[3];
    ss = sd[4] + sd[5] + sd[6] + sd[7];
    float mean = s * (1.0f / 1024.0f);
    float var  = (ss - s * mean) * (1.0f / 1023.0f);
    float rs = rsqrtf(var + 1e-6f);
    float4 a = ((const float4*)alpha)[tid];
    float4 bt = ((const float4*)beta)[tid];
    bf16x4 o;
    o[0] = (bf16)(a.x * (v.x - mean) * rs + bt.x);
    o[1] = (bf16)(a.y * (v.y - mean) * rs + bt.y);
    o[2] = (bf16)(a.z * (v.z - mean) * rs + bt.z);
    o[3] = (bf16)(a.w * (v.w - mean) * rs + bt.w);
    *(bf16x4*)(Y + (size_t)row * D_MODEL + tid * 4) = o;
}

__global__ __launch_bounds__(256) void prep_norm_kernel(
    const float* __restrict__ x, const float* __restrict__ alpha1,
    const float* __restrict__ beta1, bf16* __restrict__ xn,
    const float* __restrict__ Wq, const float* __restrict__ Wk,
    const float* __restrict__ Wv, const float* __restrict__ Wo,
    const float* __restrict__ W1, const float* __restrict__ W2,
    const float* __restrict__ bq, const float* __restrict__ bk,
    const float* __restrict__ bv,
    bf16* __restrict__ Wqkv_t, bf16* __restrict__ Wo_t,
    bf16* __restrict__ W1_t, bf16* __restrict__ W2_t,
    float* __restrict__ b_qkv)
{
    __shared__ bf16 t[64][72];
    int id = blockIdx.x;
    if (id < 4096) {
        norm_row(x, alpha1, beta1, xn, id);
        return;
    }
    id -= 4096;
    if (id < 1024) {
        int which = id >> 8, tile = id & 255;
        const float* src = which == 0 ? Wq : which == 1 ? Wk : which == 2 ? Wv : Wo;
        bf16* dst = which == 3 ? Wo_t : Wqkv_t + (size_t)which * 1024 * 1024;
        tile_tcvt(src, 1024, 1024, dst, tile & 15, tile >> 4, t);
    } else if (id < 1152) {
        int tile = id - 1024;
        tile_tcvt(W1, 1024, 512, W1_t, tile & 7, tile >> 3, t);
    } else if (id < 1280) {
        int tile = id - 1152;
        tile_tcvt(W2, 512, 1024, W2_t, tile & 15, tile >> 4, t);
    } else {
        int i = (id - 1280) * 256 + threadIdx.x;
        float v;
        if (i < 1024) v = bq[i];
        else if (i < 2048) v = bk[i - 1024];
        else v = bv[i - 2048];
        b_qkv[i] = v;
    }
}

// ---------------- LayerNorm standalone (norm2) ----------------
__global__ __launch_bounds__(256) void norm_kernel(
    const float* __restrict__ X, const float* __restrict__ alpha,
    const float* __restrict__ beta, bf16* __restrict__ Y)
{
    norm_row(X, alpha, beta, Y, blockIdx.x);
}

// ---------------- GEMM: C = A(MxK,lda)@Bt^T + bias [+Rb/+Rf] [ReLU] ----------------
// Tile BM x BN, K-step 32*KU, 4 waves (2x2), mfma 16x16x32.
// BM=64 for the short-K GEMMs (R10: 2->4 blocks/CU, -6 us). BM=128 for QKV
// (R12: BM=64 regressed — doubled B-panel staging outweighed extra waves).
// BN=32: B-tile staged by first 128 threads only (wave-uniform guard).
// VFUSE: n>=2048 columns (V proj) written transposed into vT[bh][d][s].
template <typename OutT, int BM, int BN, int KU, bool VFUSE>
__global__ __launch_bounds__(256) void gemm128(
    const bf16* __restrict__ A, const bf16* __restrict__ Bt,
    const float* __restrict__ bias, const bf16* __restrict__ Rb,
    const float* __restrict__ Rf, OutT* __restrict__ C, bf16* __restrict__ vT,
    int M, int N, int K, int lda, int relu)
{
    constexpr int MT = BM / 32;
    constexpr int NT = BN / 32;
    constexpr int ASTR = BM * 32;
    constexpr int BSTR = BN * 32;
    __shared__ bf16 As[ASTR * KU];
    __shared__ bf16 Bs[BSTR * KU];

    int tid = threadIdx.x;
    int wave = tid >> 6, lane = tid & 63;
    int quad = lane >> 4, l16 = lane & 15;
    int m0 = blockIdx.y * BM, n0 = blockIdx.x * BN;
    int wm = (wave >> 1) * (BM / 2), wn = (wave & 1) * (BN / 2);

    f32x4 acc[MT][NT] = {};

    const bf16* ga = A  + (size_t)(m0 + (tid >> 2)) * lda + (tid & 3) * 8;
    const bf16* gb = Bt + (size_t)(n0 + (tid >> 2)) * K   + (tid & 3) * 8;
    bf16* lAs = As + wave * 512;
    bf16* lBs = Bs + wave * 512;

    for (int k0 = 0; k0 < K; k0 += 32 * KU) {
        __syncthreads();
#pragma unroll
        for (int u = 0; u < KU; ++u) {
            glds16(ga + k0 + u * 32, lAs + u * ASTR);
            if (BM == 128)
                glds16(ga + (size_t)64 * lda + k0 + u * 32, lAs + u * ASTR + 2048);
            if (BN >= 64 || tid < 128)
                glds16(gb + k0 + u * 32, lBs + u * BSTR);
            if (BN == 128) glds16(gb + (size_t)64 * K + k0 + u * 32, lBs + u * BSTR + 2048);
        }
        __syncthreads();
#pragma unroll
        for (int u = 0; u < KU; ++u) {
            bf16x8 af[MT], bfr[NT];
#pragma unroll
            for (int mt = 0; mt < MT; ++mt)
                af[mt] = *(const bf16x8*)(As + u * ASTR + (wm + mt * 16 + l16) * 32 + quad * 8);
#pragma unroll
            for (int nt = 0; nt < NT; ++nt)
                bfr[nt] = *(const bf16x8*)(Bs + u * BSTR + (wn + nt * 16 + l16) * 32 + quad * 8);
#pragma unroll
            for (int mt = 0; mt < MT; ++mt)
#pragma unroll
                for (int nt = 0; nt < NT; ++nt)
                    acc[mt][nt] = __builtin_amdgcn_mfma_f32_16x16x32_bf16(af[mt], bfr[nt], acc[mt][nt], 0, 0, 0);
        }
    }

#pragma unroll
    for (int nt = 0; nt < NT; ++nt) {
        int n = n0 + wn + nt * 16 + l16;
        float bv = bias[n];
        if (VFUSE && n >= 2048) {
            int d = n & 63, h = (n - 2048) >> 6;
#pragma unroll
            for (int mt = 0; mt < MT; ++mt) {
                int m = m0 + wm + mt * 16 + quad * 4;
                int b = m >> 11, sidx = m & 2047;
                bf16x4 pk;
#pragma unroll
                for (int r = 0; r < 4; ++r) pk[r] = (bf16)(acc[mt][nt][r] + bv);
                *(bf16x4*)(vT + (((size_t)(b * 16 + h) * 64 + d) * SEQ + sidx)) = pk;
            }
        } else {
#pragma unroll
            for (int mt = 0; mt < MT; ++mt) {
#pragma unroll
                for (int r = 0; r < 4; ++r) {
                    int m = m0 + wm + mt * 16 + quad * 4 + r;
                    float vv = acc[mt][nt][r] + bv;
                    if (Rb) vv += (float)Rb[(size_t)m * N + n];
                    if (Rf) vv += Rf[(size_t)m * N + n];
                    if (relu) vv = vv > 0.0f ? vv : 0.0f;
                    C[(size_t)m * N + n] = (OutT)vv;
                }
            }
        }
    }
}

// ---------------- Flash attention, dh=64, fixed-max softmax ----------------
// CLOSED at the R6/R10 variant (64.9 us measured): S^T QK -> Ps LDS buffer
// -> PV, K/V double-buffered in LDS, ONE barrier/tile, 2 blocks/CU.
// Tried and rejected: split-K (R1), in-register permlane P (R2), K=16 PV
// (R4), cross-tile pipeline (R7/R8: +12 VGPR -> 1 block/CU), V-unstaging
// (R11: 2x V traffic + exposed L2 latency).
__global__ __launch_bounds__(512) void attn_kernel(
    const bf16* __restrict__ qkv, const bf16* __restrict__ vT, bf16* __restrict__ O)
{
    __shared__ __align__(16) char smem[57344];
    // buf b at smem + b*18432: Ks [64][72] then Vt [64][72]
    bf16* Ps = (bf16*)(smem + 36864);    // [8 waves][32 q][40 keys-padded]

    int tid = threadIdx.x;
    int wave = tid >> 6, lane = tid & 63;
    int quad = lane >> 4, l16 = lane & 15;
    int qg = wave >> 1, kg = wave & 1;
    int bh = blockIdx.y, b = bh >> 4, h = bh & 15;
    int q0 = blockIdx.x * 128 + qg * 32;

    const bf16* Qb = qkv + (size_t)(b * SEQ + q0) * 3072 + h * 64;
    const bf16* Kb = qkv + (size_t)(b * SEQ) * 3072 + 1024 + h * 64;
    const bf16* Vb = vT + (size_t)bh * 64 * SEQ;

    const float c_l2 = 0.125f * LOG2E;
    bf16x8 qa[2][2];
#pragma unroll
    for (int mt = 0; mt < 2; ++mt)
#pragma unroll
        for (int hf = 0; hf < 2; ++hf) {
            bf16x8 raw = *(const bf16x8*)(Qb + (size_t)(mt * 16 + l16) * 3072 + hf * 32 + quad * 8);
            bf16x8 sc;
#pragma unroll
            for (int j = 0; j < 8; ++j) sc[j] = (bf16)((float)raw[j] * c_l2);
            qa[mt][hf] = sc;
        }

    float lsum[2] = {};
    f32x4 oacc[2][4] = {};

    int sr = tid >> 3, scol = (tid & 7) * 8;   // 64 rows x 8 chunks (512 thr)
    const bf16* kp = Kb + (size_t)sr * 3072 + scol;
    const bf16* vp = Vb + (size_t)sr * SEQ + scol;
    bf16x8 kr = *(const bf16x8*)kp;
    bf16x8 vr = *(const bf16x8*)vp;

    bf16* PsW = Ps + wave * 32 * 40;

    // prologue: stage tile 0 into buf0; prefetch tile 1 into regs
    {
        bf16* K0 = (bf16*)smem;
        *(bf16x8*)(K0 + sr * 72 + scol) = kr;
        *(bf16x8*)(K0 + 4608 + sr * 72 + scol) = vr;
    }
    kr = *(const bf16x8*)(kp + (size_t)64 * 3072);
    vr = *(const bf16x8*)(vp + 64);
    __syncthreads();

    for (int kt = 0; kt < SEQ; kt += 64) {
        int cur = (kt >> 6) & 1;
        bf16* Ks = (bf16*)(smem + cur * 18432);
        bf16* Vt = Ks + 4608;
        const bf16* KsKg = Ks + kg * 32 * 72;

        // stage NEXT tile into the other buffer (overlaps this tile's compute)
        if (kt + 64 < SEQ) {
            bf16* Kn = (bf16*)(smem + (cur ^ 1) * 18432);
            *(bf16x8*)(Kn + sr * 72 + scol) = kr;
            *(bf16x8*)(Kn + 4608 + sr * 72 + scol) = vr;
        }
        // prefetch tile after next into regs (HBM latency hides under compute)
        if (kt + 128 < SEQ) {
            kr = *(const bf16x8*)(kp + (size_t)(kt + 128) * 3072);
            vr = *(const bf16x8*)(vp + kt + 128);
        }

        bf16x8 kb[2][2], vb[4];
#pragma unroll
        for (int t4 = 0; t4 < 2; ++t4) {
            kb[t4][0] = *(const bf16x8*)(KsKg + (t4 * 16 + l16) * 72 + quad * 8);
            kb[t4][1] = *(const bf16x8*)(KsKg + (t4 * 16 + l16) * 72 + 32 + quad * 8);
        }
#pragma unroll
        for (int dt = 0; dt < 4; ++dt)
            vb[dt] = *(const bf16x8*)(Vt + (dt * 16 + l16) * 72 + kg * 32 + quad * 8);

        // S^T over this wave's 32 keys: rows = keys, col = q (l16)
#pragma unroll
        for (int mt = 0; mt < 2; ++mt)
#pragma unroll
            for (int t4 = 0; t4 < 2; ++t4) {
                f32x4 c = {};
                c = __builtin_amdgcn_mfma_f32_16x16x32_bf16(kb[t4][0], qa[mt][0], c, 0, 0, 0);
                c = __builtin_amdgcn_mfma_f32_16x16x32_bf16(kb[t4][1], qa[mt][1], c, 0, 0, 0);
                bf16x4 pk;
                float psum = 0.0f;
#pragma unroll
                for (int r = 0; r < 4; ++r) {
                    float p = exp2f(c[r]);
                    psum += p;
                    pk[r] = (bf16)p;
                }
                lsum[mt] += psum;
                *(bf16x4*)(PsW + (mt * 16 + l16) * 40 + t4 * 16 + quad * 4) = pk;
            }
        // PV over this wave's 32 keys (K=32 mfma)
#pragma unroll
        for (int mt = 0; mt < 2; ++mt) {
            bf16x8 pa = *(const bf16x8*)(PsW + (mt * 16 + l16) * 40 + quad * 8);
#pragma unroll
            for (int dt = 0; dt < 4; ++dt)
                oacc[mt][dt] = __builtin_amdgcn_mfma_f32_16x16x32_bf16(pa, vb[dt], oacc[mt][dt], 0, 0, 0);
        }

        __syncthreads();   // single barrier per tile
    }

    // cross-quad lsum reduce (per q = mt*16 + l16)
    float lr[2];
#pragma unroll
    for (int mt = 0; mt < 2; ++mt) {
        lr[mt] = lsum[mt];
        lr[mt] += __shfl_xor(lr[mt], 16);
        lr[mt] += __shfl_xor(lr[mt], 32);
    }
    // merge the two key-groups via LDS (Ks/Vt/Ps dead now; loop barrier passed)
    float* sf = (float*)smem;                  // [qg][d 64][q 32]
    float* lb = sf + 8192;                     // [qg][mt][16]
    if (kg == 1) {
#pragma unroll
        for (int mt = 0; mt < 2; ++mt)
#pragma unroll
            for (int dt = 0; dt < 4; ++dt)
                *(f32x4*)&sf[qg * 2048 + (dt * 16 + l16) * 32 + mt * 16 + quad * 4] = oacc[mt][dt];
        if (lane < 16) {
            lb[(qg * 2 + 0) * 16 + l16] = lr[0];
            lb[(qg * 2 + 1) * 16 + l16] = lr[1];
        }
    }
    __syncthreads();
    if (kg == 0) {
#pragma unroll
        for (int mt = 0; mt < 2; ++mt) {
            lr[mt] += lb[(qg * 2 + mt) * 16 + l16];
#pragma unroll
            for (int dt = 0; dt < 4; ++dt) {
                f32x4 other = *(const f32x4*)&sf[qg * 2048 + (dt * 16 + l16) * 32 + mt * 16 + quad * 4];
                oacc[mt][dt] += other;
            }
        }
#pragma unroll
        for (int mt = 0; mt < 2; ++mt)
#pragma unroll
            for (int r = 0; r < 4; ++r) {
                float inv = 1.0f / __shfl(lr[mt], quad * 4 + r, 16);
                int row = b * SEQ + q0 + mt * 16 + quad * 4 + r;
                bf16* op = O + (size_t)row * D_MODEL + h * 64;
#pragma unroll
                for (int dt = 0; dt < 4; ++dt)
                    op[dt * 16 + l16] = (bf16)(oacc[mt][dt][r] * inv);
            }
    }
}

// ---------------- launch ----------------
extern "C" void kernel_launch(void* const* d_in, const int* in_sizes, int n_in,
                              void* d_out, int out_size, void* d_ws, size_t ws_size,
                              hipStream_t stream)
{
    const float* x      = (const float*)d_in[0];
    const float* Wq     = (const float*)d_in[1];
    const float* bq     = (const float*)d_in[2];
    const float* Wk     = (const float*)d_in[3];
    const float* bk     = (const float*)d_in[4];
    const float* Wv     = (const float*)d_in[5];
    const float* bv     = (const float*)d_in[6];
    const float* Wo     = (const float*)d_in[7];
    const float* bo     = (const float*)d_in[8];
    const float* alpha1 = (const float*)d_in[9];
    const float* beta1  = (const float*)d_in[10];
    const float* alpha2 = (const float*)d_in[11];
    const float* beta2  = (const float*)d_in[12];
    const float* W1     = (const float*)d_in[13];
    const float* b1     = (const float*)d_in[14];
    const float* W2     = (const float*)d_in[15];
    const float* b2     = (const float*)d_in[16];

    char* ws = (char*)d_ws;
    const size_t MB = 1ull << 20;
    bf16*  Wqkv_t = (bf16*)(ws + 0 * MB);    // 6 MB
    bf16*  Wo_t   = (bf16*)(ws + 6 * MB);    // 2 MB
    bf16*  W1_t   = (bf16*)(ws + 8 * MB);    // 1 MB
    bf16*  W2_t   = (bf16*)(ws + 9 * MB);    // 1 MB
    float* b_qkv  = (float*)(ws + 10 * MB);
    bf16*  xn     = (bf16*)(ws + 11 * MB);   // 8 MB (live until Wo epilogue)
    bf16*  qkv    = (bf16*)(ws + 19 * MB);   // 24 MB (q,k live until attn)
    bf16*  vT     = (bf16*)(ws + 43 * MB);   // 8 MB (dead after attn)
    bf16*  o      = (bf16*)(ws + 51 * MB);   // 8 MB (dead after Wo)
    float* x2     = (float*)(ws + 19 * MB);  // fp32 16 MB over dead qkv head
    bf16*  hn     = (bf16*)(ws + 35 * MB);   // 8 MB over dead qkv tail
    bf16*  h1     = (bf16*)(ws + 11 * MB);   // 4 MB over dead xn

    const int M = NB * SEQ;

    prep_norm_kernel<<<4096 + 1292, 256, 0, stream>>>(
        x, alpha1, beta1, xn, Wq, Wk, Wv, Wo, W1, W2, bq, bk, bv,
        Wqkv_t, Wo_t, W1_t, W2_t, b_qkv);

    // fused QKV GEMM, BM=128/KU=2 (3 blocks/CU; BM=64 regressed in R12),
    // V written transposed
    gemm128<bf16, 128, 128, 2, true><<<dim3(24, 32), 256, 0, stream>>>(
        xn, Wqkv_t, b_qkv, nullptr, nullptr, qkv, vT, M, 3072, D_MODEL, D_MODEL, 0);

    attn_kernel<<<dim3(SEQ / 128, 32), 512, 0, stream>>>(qkv, vT, o);

    // x2 = xn + o @ Wo + bo  (BM=64: 1024 blocks = 4/CU)
    gemm128<float, 64, 64, 4, false><<<dim3(16, 64), 256, 0, stream>>>(
        o, Wo_t, bo, xn, nullptr, x2, nullptr, M, D_MODEL, D_MODEL, D_MODEL, 0);

    norm_kernel<<<M, 256, 0, stream>>>(x2, alpha2, beta2, hn);

    // FFN1: h1 = relu(hn @ W1 + b1), BM=64/BN=32: 1024 blocks = 4/CU
    gemm128<bf16, 64, 32, 4, false><<<dim3(16, 64), 256, 0, stream>>>(
        hn, W1_t, b1, nullptr, nullptr, h1, nullptr, M, 512, D_MODEL, D_MODEL, 1);

    // out = x2 + h1 @ W2 + b2  (BM=64: 1024 blocks = 4/CU)
    gemm128<float, 64, 64, 4, false><<<dim3(16, 64), 256, 0, stream>>>(
        h1, W2_t, b2, nullptr, x2, (float*)d_out, nullptr, M, D_MODEL, 512, 512, 0);
}